// Round 4
// baseline (331.861 us; speedup 1.0000x reference)
//
#include <hip/hip_runtime.h>
#include <stdint.h>

#define NN 8192      // nodes
#define FF 512       // feature dim
#define HH 64        // hidden
#define CC 10        // classes
#define EE 262144    // edges
#define NTR 512      // train nodes
#define ALPHA_NS 0.2f

#define DB_NB 64           // dedup blocks (src-slice owners)
#define DB_SL (NN / DB_NB) // 128 srcs per slice
#define DB_HS 8192         // LDS hash slots per block
#define HB_NB 64           // hist/scatter blocks
#define HB_EPB (EE / HB_NB) // 4096 edges per block

__device__ __forceinline__ float dot4(float4 a, float4 b){
    return a.x*b.x + a.y*b.y + a.z*b.z + a.w*b.w;
}

// v0[f] = sum_h W[h][f]*a[h] ; v1[f] = sum_h W[h][f]*a[HH+h]; also zero mark[]
__global__ void k_v01(const float* __restrict__ W, const float* __restrict__ a,
                      float* __restrict__ v01, uint32_t* __restrict__ mark){
    int f = threadIdx.x;   // 1 block x 512
    #pragma unroll
    for (int i = 0; i < NN/FF; ++i) mark[f + i*FF] = 0u;
    float acc0 = 0.f, acc1 = 0.f;
    for (int hh = 0; hh < HH; ++hh){
        float w = W[hh*FF + f];
        acc0 += w * a[hh];
        acc1 += w * a[HH + hh];
    }
    v01[f] = acc0;
    v01[FF + f] = acc1;
}

// wave per row: s_src[r] = h[r]·v0 ; s_dst[r] = h[r]·v1
__global__ void k_sdots(const float* __restrict__ h, const float* __restrict__ v01,
                        float* __restrict__ s_src, float* __restrict__ s_dst){
    int row = blockIdx.x*4 + (threadIdx.x >> 6);
    int lane = threadIdx.x & 63;
    const float4* hr = (const float4*)(h + (size_t)row*FF);
    const float4* v0 = (const float4*)v01;
    const float4* v1 = (const float4*)(v01 + FF);
    float4 x0 = hr[lane*2], x1 = hr[lane*2+1];
    float a0 = dot4(x0, v0[lane*2]) + dot4(x1, v0[lane*2+1]);
    float a1 = dot4(x0, v1[lane*2]) + dot4(x1, v1[lane*2+1]);
    #pragma unroll
    for (int off = 32; off >= 1; off >>= 1){
        a0 += __shfl_xor(a0, off);
        a1 += __shfl_xor(a1, off);
    }
    if (lane == 0){ s_src[row] = a0; s_dst[row] = a1; }
}

// FW[r][c] = features[r] · W1[c]
__global__ void k_fw(const float* __restrict__ feat, const float* __restrict__ W1,
                     float* __restrict__ FW){
    int row = blockIdx.x*4 + (threadIdx.x >> 6);
    int lane = threadIdx.x & 63;
    const float4* fr = (const float4*)(feat + (size_t)row*FF);
    float4 x0 = fr[lane*2], x1 = fr[lane*2+1];
    float acc[CC];
    #pragma unroll
    for (int c = 0; c < CC; ++c){
        const float4* wr = (const float4*)(W1 + c*FF);
        acc[c] = dot4(x0, wr[lane*2]) + dot4(x1, wr[lane*2+1]);
    }
    #pragma unroll
    for (int c = 0; c < CC; ++c){
        float r = acc[c];
        #pragma unroll
        for (int off = 32; off >= 1; off >>= 1) r += __shfl_xor(r, off);
        acc[c] = r;
    }
    if (lane == 0){
        #pragma unroll
        for (int c = 0; c < CC; ++c) FW[row*CC + c] = acc[c];
    }
}

// class frequencies over train set + train-node marker (mark pre-zeroed by k_v01)
__global__ void k_cvec(const int* __restrict__ idx_train, const int* __restrict__ labels,
                       float* __restrict__ cvec, uint32_t* __restrict__ mark){
    __shared__ int hist[CC];
    if (threadIdx.x < CC) hist[threadIdx.x] = 0;
    __syncthreads();
    for (int t = threadIdx.x; t < NTR; t += blockDim.x){
        int node = idx_train[t];
        mark[node] = 1u;
        atomicAdd(&hist[labels[node]], 1);
    }
    __syncthreads();
    if (threadIdx.x < CC) cvec[threadIdx.x] = (float)hist[threadIdx.x] / (float)NTR;
}

// src-slice owner blocks: LDS-hash dedup + e compute + LDS s1 accumulation.
// No global atomics. Every edge k gets e_val[k] written (e or -1).
__global__ __launch_bounds__(1024) void k_dedup(const int* __restrict__ ei,
                        const float* __restrict__ s_src, const float* __restrict__ s_dst,
                        float* __restrict__ e_val, float* __restrict__ s1){
    __shared__ uint32_t hsh[DB_HS];
    __shared__ float ssl[DB_SL];
    __shared__ float s1l[DB_SL];
    int t = threadIdx.x;
    int base = blockIdx.x * DB_SL;
    for (int i = t; i < DB_HS; i += 1024) hsh[i] = 0xFFFFFFFFu;
    if (t < DB_SL){ ssl[t] = s_src[base + t]; s1l[t] = 0.f; }
    __syncthreads();
    for (int k = t; k < EE; k += 1024){
        int src = ei[k];
        unsigned ls = (unsigned)(src - base);
        if (ls < DB_SL){
            int dst = ei[EE + k];
            uint32_t key = (ls << 13) | (uint32_t)dst;      // 20-bit key, != EMPTY
            uint32_t slot = (key * 2654435761u) >> 19;      // top 13 bits
            bool owner = false;
            for (uint32_t probe = 0; probe < DB_HS; ++probe){
                uint32_t prev = atomicCAS(&hsh[slot], 0xFFFFFFFFu, key);
                if (prev == 0xFFFFFFFFu){ owner = true; break; }
                if (prev == key) break;                      // duplicate pair -> drop
                slot = (slot + 1u) & (DB_HS - 1u);
            }
            if (owner){
                float z = ssl[ls] + s_dst[dst];
                z = (z >= 0.f) ? z : ALPHA_NS * z;
                float e = expf(z);
                e_val[k] = e;
                atomicAdd(&s1l[ls], e);                      // LDS float atomic
            } else {
                e_val[k] = -1.0f;
            }
        }
    }
    __syncthreads();
    if (t < DB_SL) s1[base + t] = s1l[t];
}

// per-block dst histogram over valid edges -> coalesced partials hp[b][NN] (u16)
__global__ __launch_bounds__(512) void k_hist(const int* __restrict__ ei,
                        const float* __restrict__ e_val, uint16_t* __restrict__ hp){
    __shared__ uint32_t hist[NN];
    int t = threadIdx.x, b = blockIdx.x;
    for (int i = t; i < NN; i += 512) hist[i] = 0u;
    __syncthreads();
    int k0 = b * HB_EPB;
    for (int i = t; i < HB_EPB; i += 512){
        int k = k0 + i;
        if (e_val[k] >= 0.f) atomicAdd(&hist[ei[EE + k]], 1u);
    }
    __syncthreads();
    for (int i = t; i < NN; i += 512) hp[(size_t)b*NN + i] = (uint16_t)hist[i];
}

// per-bin cross-block exclusive prefix (pre[bin][b]) + per-bin totals
__global__ void k_pre(const uint16_t* __restrict__ hp, uint16_t* __restrict__ pre,
                      uint32_t* __restrict__ tot){
    int bin = blockIdx.x*blockDim.x + threadIdx.x;   // 8192 threads
    uint32_t sum = 0;
    #pragma unroll
    for (int b = 0; b < HB_NB; ++b){
        pre[(size_t)bin*HB_NB + b] = (uint16_t)sum;
        sum += hp[(size_t)b*NN + bin];
    }
    tot[bin] = sum;
}

// single-block scan of (tot + selfloop) -> offs; also writes self-loop CSC entries
__global__ __launch_bounds__(1024) void k_scanA(const uint32_t* __restrict__ tot,
                        const float* __restrict__ s1, uint32_t* __restrict__ offs,
                        uint32_t* __restrict__ csc_src, float* __restrict__ csc_w){
    __shared__ uint32_t part[1024];
    int t = threadIdx.x;
    uint32_t local[8];
    uint32_t sum = 0;
    #pragma unroll
    for (int i = 0; i < 8; ++i){
        int idx = t*8 + i;
        uint32_t v = tot[idx] + (s1[idx] == 0.0f ? 1u : 0u);
        local[i] = v; sum += v;
    }
    part[t] = sum;
    __syncthreads();
    for (int off = 1; off < 1024; off <<= 1){
        uint32_t v = (t >= off) ? part[t - off] : 0u;
        __syncthreads();
        part[t] += v;
        __syncthreads();
    }
    uint32_t base = (t > 0) ? part[t-1] : 0u;
    #pragma unroll
    for (int i = 0; i < 8; ++i){
        int idx = t*8 + i;
        offs[idx] = base;
        uint32_t v = local[i];
        if (s1[idx] == 0.0f){            // zero-out-degree row -> self-loop at row end
            csc_src[base + v - 1] = (uint32_t)idx;
            csc_w[base + v - 1] = 1.0f;
        }
        base += v;
    }
    if (t == 1023) offs[NN] = base;
}

// scatter valid edges into CSC using LDS ranks (same blocking as k_hist)
__global__ __launch_bounds__(512) void k_scatter(const int* __restrict__ ei,
                        const float* __restrict__ e_val, const float* __restrict__ s1,
                        const uint32_t* __restrict__ offs, const uint16_t* __restrict__ pre,
                        uint32_t* __restrict__ csc_src, float* __restrict__ csc_w){
    __shared__ uint32_t rnk[NN];
    int t = threadIdx.x, b = blockIdx.x;
    for (int i = t; i < NN; i += 512) rnk[i] = 0u;
    __syncthreads();
    int k0 = b * HB_EPB;
    for (int i = t; i < HB_EPB; i += 512){
        int k = k0 + i;
        float e = e_val[k];
        if (e >= 0.f){
            int src = ei[k], dst = ei[EE + k];
            uint32_t r = atomicAdd(&rnk[dst], 1u);
            uint32_t pos = offs[dst] + (uint32_t)pre[(size_t)dst*HB_NB + b] + r;
            csc_src[pos] = (uint32_t)src;
            csc_w[pos] = e / s1[src];
        }
    }
}

// Db (= b since d≈1) and ut after t=1 (ut1 = Db since ut0 = 0)
__global__ void k_db(const int* __restrict__ labels, const uint32_t* __restrict__ mark,
                     const float* __restrict__ cvec, float* __restrict__ Db,
                     float* __restrict__ ua){
    int g = blockIdx.x*blockDim.x + threadIdx.x;
    if (g >= NN*CC) return;
    int i = g / CC, c = g - i*CC;
    float v = 0.f;
    if (mark[i]) v = ((labels[i] == c) ? 1.0f : 0.0f) - cvec[c];
    Db[g] = v;
    ua[g] = v;
}

// one diffusion step: uout[i,:] = sum_{p in CSC row i} w[p]*uin[src[p],:] + Db[i,:] (+FW)
__global__ void k_spmv(const uint32_t* __restrict__ offs, const uint32_t* __restrict__ csrc,
                       const float* __restrict__ cw, const float* __restrict__ uin,
                       const float* __restrict__ Db, const float* __restrict__ FW,
                       float* __restrict__ uout){
    int row = blockIdx.x*4 + (threadIdx.x >> 6);
    int lane = threadIdx.x & 63;
    uint32_t s = offs[row], e = offs[row+1];
    float acc[CC];
    #pragma unroll
    for (int c = 0; c < CC; ++c) acc[c] = 0.f;
    for (uint32_t p = s + lane; p < e; p += 64){
        uint32_t src = csrc[p];
        float w = cw[p];
        const float2* u2 = (const float2*)(uin + (size_t)src*CC);
        #pragma unroll
        for (int q = 0; q < 5; ++q){
            float2 v = u2[q];
            acc[2*q]   += w * v.x;
            acc[2*q+1] += w * v.y;
        }
    }
    #pragma unroll
    for (int c = 0; c < CC; ++c){
        float r = acc[c];
        #pragma unroll
        for (int off = 32; off >= 1; off >>= 1) r += __shfl_xor(r, off);
        acc[c] = r;
    }
    if (lane == 0){
        const float* db = Db + row*CC;
        float* o = uout + row*CC;
        if (FW){
            const float* fw = FW + row*CC;
            #pragma unroll
            for (int c = 0; c < CC; ++c) o[c] = acc[c] + db[c] + fw[c];
        } else {
            #pragma unroll
            for (int c = 0; c < CC; ++c) o[c] = acc[c] + db[c];
        }
    }
}

extern "C" void kernel_launch(void* const* d_in, const int* in_sizes, int n_in,
                              void* d_out, int out_size, void* d_ws, size_t ws_size,
                              hipStream_t stream){
    const float* h    = (const float*)d_in[0];
    const float* W    = (const float*)d_in[1];
    const float* a    = (const float*)d_in[2];
    const float* W1   = (const float*)d_in[3];
    const float* feat = (const float*)d_in[4];
    const int* ei     = (const int*)d_in[5];
    const int* idx_tr = (const int*)d_in[6];
    const int* labels = (const int*)d_in[7];
    float* out = (float*)d_out;

    char* wsp = (char*)d_ws;
    auto alloc = [&](size_t bytes)->void*{
        void* p = (void*)wsp;
        wsp += (bytes + 255) & ~(size_t)255;
        return p;
    };
    float*    e_val  = (float*)   alloc((size_t)EE*4);              // 1 MB
    uint16_t* hp     = (uint16_t*)alloc((size_t)HB_NB*NN*2);        // 1 MB
    uint16_t* pre    = (uint16_t*)alloc((size_t)NN*HB_NB*2);        // 1 MB
    uint32_t* tot    = (uint32_t*)alloc(NN*4);
    uint32_t* offs   = (uint32_t*)alloc((NN+1)*4);
    float*    s1     = (float*)   alloc(NN*4);
    uint32_t* mark   = (uint32_t*)alloc(NN*4);
    uint32_t* csrc   = (uint32_t*)alloc((size_t)(EE+NN)*4);         // 1.05 MB
    float*    cw     = (float*)   alloc((size_t)(EE+NN)*4);         // 1.05 MB
    float*    v01    = (float*)   alloc(2*FF*4);
    float*    s_src  = (float*)   alloc(NN*4);
    float*    s_dst  = (float*)   alloc(NN*4);
    float*    FW     = (float*)   alloc((size_t)NN*CC*4);
    float*    cvec   = (float*)   alloc(CC*4);
    float*    Db     = (float*)   alloc((size_t)NN*CC*4);
    float*    ua     = (float*)   alloc((size_t)NN*CC*4);
    float*    ub     = (float*)   alloc((size_t)NN*CC*4);

    k_v01    <<<1, FF, 0, stream>>>(W, a, v01, mark);
    k_sdots  <<<NN/4, 256, 0, stream>>>(h, v01, s_src, s_dst);
    k_fw     <<<NN/4, 256, 0, stream>>>(feat, W1, FW);
    k_cvec   <<<1, 512, 0, stream>>>(idx_tr, labels, cvec, mark);
    k_dedup  <<<DB_NB, 1024, 0, stream>>>(ei, s_src, s_dst, e_val, s1);
    k_hist   <<<HB_NB, 512, 0, stream>>>(ei, e_val, hp);
    k_pre    <<<NN/256, 256, 0, stream>>>(hp, pre, tot);
    k_scanA  <<<1, 1024, 0, stream>>>(tot, s1, offs, csrc, cw);
    k_scatter<<<HB_NB, 512, 0, stream>>>(ei, e_val, s1, offs, pre, csrc, cw);
    k_db     <<<(NN*CC)/256, 256, 0, stream>>>(labels, mark, cvec, Db, ua);

    float* cur = ua;
    float* nxt = ub;
    for (int t = 2; t <= 10; ++t){
        float* dst = (t == 10) ? out : nxt;
        const float* fwp = (t == 7) ? FW : nullptr;
        k_spmv<<<NN/4, 256, 0, stream>>>(offs, csrc, cw, cur, Db, fwp, dst);
        float* tmp = cur; cur = dst; nxt = tmp;
    }
}

// Round 5
// 209.714 us; speedup vs baseline: 1.5824x; 1.5824x over previous
//
#include <hip/hip_runtime.h>
#include <stdint.h>

#define NN 8192      // nodes
#define FF 512       // feature dim
#define HH 64        // hidden
#define CC 10        // classes
#define EE 262144    // edges
#define NTR 512      // train nodes
#define ALPHA_NS 0.2f

#define HTAB_BITS 19
#define HTAB_CAP (1u << HTAB_BITS)
#define HB_NB 64            // hist/scatter blocks
#define HB_EPB (EE / HB_NB) // 4096 edges per block

__device__ __forceinline__ float dot4(float4 a, float4 b){
    return a.x*b.x + a.y*b.y + a.z*b.z + a.w*b.w;
}

// v0[f] = sum_h W[h][f]*a[h] ; v1[f] = sum_h W[h][f]*a[HH+h]
__global__ void k_v01(const float* __restrict__ W, const float* __restrict__ a,
                      float* __restrict__ v01){
    int f = threadIdx.x;   // 1 block x 512
    float acc0 = 0.f, acc1 = 0.f;
    for (int hh = 0; hh < HH; ++hh){
        float w = W[hh*FF + f];
        acc0 += w * a[hh];
        acc1 += w * a[HH + hh];
    }
    v01[f] = acc0;
    v01[FF + f] = acc1;
}

// wave per row: s_src[r] = h[r]·v0 ; s_dst[r] = h[r]·v1
__global__ void k_sdots(const float* __restrict__ h, const float* __restrict__ v01,
                        float* __restrict__ s_src, float* __restrict__ s_dst){
    int row = blockIdx.x*4 + (threadIdx.x >> 6);
    int lane = threadIdx.x & 63;
    const float4* hr = (const float4*)(h + (size_t)row*FF);
    const float4* v0 = (const float4*)v01;
    const float4* v1 = (const float4*)(v01 + FF);
    float4 x0 = hr[lane*2], x1 = hr[lane*2+1];
    float a0 = dot4(x0, v0[lane*2]) + dot4(x1, v0[lane*2+1]);
    float a1 = dot4(x0, v1[lane*2]) + dot4(x1, v1[lane*2+1]);
    #pragma unroll
    for (int off = 32; off >= 1; off >>= 1){
        a0 += __shfl_xor(a0, off);
        a1 += __shfl_xor(a1, off);
    }
    if (lane == 0){ s_src[row] = a0; s_dst[row] = a1; }
}

// FW[r][c] = features[r] · W1[c]
__global__ void k_fw(const float* __restrict__ feat, const float* __restrict__ W1,
                     float* __restrict__ FW){
    int row = blockIdx.x*4 + (threadIdx.x >> 6);
    int lane = threadIdx.x & 63;
    const float4* fr = (const float4*)(feat + (size_t)row*FF);
    float4 x0 = fr[lane*2], x1 = fr[lane*2+1];
    float acc[CC];
    #pragma unroll
    for (int c = 0; c < CC; ++c){
        const float4* wr = (const float4*)(W1 + c*FF);
        acc[c] = dot4(x0, wr[lane*2]) + dot4(x1, wr[lane*2+1]);
    }
    #pragma unroll
    for (int c = 0; c < CC; ++c){
        float r = acc[c];
        #pragma unroll
        for (int off = 32; off >= 1; off >>= 1) r += __shfl_xor(r, off);
        acc[c] = r;
    }
    if (lane == 0){
        #pragma unroll
        for (int c = 0; c < CC; ++c) FW[row*CC + c] = acc[c];
    }
}

// fused: class frequencies over train set + Db/ua init (single block, LDS mark)
__global__ __launch_bounds__(1024) void k_cvdb(const int* __restrict__ idx_train,
                        const int* __restrict__ labels,
                        float* __restrict__ Db, float* __restrict__ ua){
    __shared__ uint8_t lmark[NN];
    __shared__ int chist[CC];
    __shared__ float cvecl[CC];
    int t = threadIdx.x;
    for (int i = t; i < NN; i += 1024) lmark[i] = 0;
    if (t < CC) chist[t] = 0;
    __syncthreads();
    if (t < NTR){
        int node = idx_train[t];
        lmark[node] = 1;
        atomicAdd(&chist[labels[node]], 1);
    }
    __syncthreads();
    if (t < CC) cvecl[t] = (float)chist[t] / (float)NTR;
    __syncthreads();
    for (int g = t; g < NN*CC; g += 1024){
        int i = g / CC, c = g - i*CC;
        float v = 0.f;
        if (lmark[i]) v = ((labels[i] == c) ? 1.0f : 0.0f) - cvecl[c];
        Db[g] = v;
        ua[g] = v;
    }
}

// one edge per thread: global-CAS dedup (htab pre-set to 0xFF) + e compute.
// No global atomicAdds. Duplicate pairs carry identical values, so any winner
// yields the same e; losers write -1.
__global__ void k_dedupG(const int* __restrict__ ei, const float* __restrict__ s_src,
                         const float* __restrict__ s_dst, uint32_t* __restrict__ htab,
                         float* __restrict__ e_val){
    int k = blockIdx.x*256 + threadIdx.x;
    int src = ei[k], dst = ei[EE + k];
    uint32_t key = ((uint32_t)src << 13) | (uint32_t)dst;   // 26-bit, != EMPTY
    uint32_t slot = (key * 2654435761u) >> (32 - HTAB_BITS);
    bool owner = false;
    for (uint32_t p = 0; p < HTAB_CAP; ++p){
        uint32_t prev = atomicCAS(&htab[slot], 0xFFFFFFFFu, key);
        if (prev == 0xFFFFFFFFu){ owner = true; break; }
        if (prev == key) break;                   // duplicate pair -> drop
        slot = (slot + 1u) & (HTAB_CAP - 1u);
    }
    if (owner){
        float z = s_src[src] + s_dst[dst];
        z = (z >= 0.f) ? z : ALPHA_NS * z;
        e_val[k] = expf(z);
    } else {
        e_val[k] = -1.0f;
    }
}

// per-block partials over valid edges: dst counts (u16 out) + src float sums (s1)
__global__ __launch_bounds__(512) void k_hist2(const int* __restrict__ ei,
                        const float* __restrict__ e_val,
                        uint16_t* __restrict__ hp, float* __restrict__ s1p){
    __shared__ uint32_t cnt[NN];   // 32 KB
    __shared__ float    s1l[NN];   // 32 KB
    int t = threadIdx.x, b = blockIdx.x;
    for (int i = t; i < NN; i += 512){ cnt[i] = 0u; s1l[i] = 0.f; }
    __syncthreads();
    int k0 = b * HB_EPB;
    for (int i = t; i < HB_EPB; i += 512){
        int k = k0 + i;
        float e = e_val[k];
        if (e >= 0.f){
            atomicAdd(&cnt[ei[EE + k]], 1u);
            atomicAdd(&s1l[ei[k]], e);
        }
    }
    __syncthreads();
    for (int i = t; i < NN; i += 512){
        hp[(size_t)b*NN + i] = (uint16_t)cnt[i];
        s1p[(size_t)b*NN + i] = s1l[i];
    }
}

// per-bin cross-block exclusive prefix + totals + final s1
__global__ void k_pre2(const uint16_t* __restrict__ hp, const float* __restrict__ s1p,
                       uint16_t* __restrict__ pre, uint32_t* __restrict__ tot,
                       float* __restrict__ s1){
    int bin = blockIdx.x*blockDim.x + threadIdx.x;   // 8192 threads
    uint32_t sum = 0;
    #pragma unroll
    for (int b = 0; b < HB_NB; ++b){
        pre[(size_t)bin*HB_NB + b] = (uint16_t)sum;
        sum += hp[(size_t)b*NN + bin];
    }
    tot[bin] = sum;
    float fs = 0.f;
    #pragma unroll
    for (int b = 0; b < HB_NB; ++b) fs += s1p[(size_t)b*NN + bin];
    s1[bin] = fs;
}

// single-block scan of (tot + selfloop) -> offs; also writes self-loop CSC entries
__global__ __launch_bounds__(1024) void k_scanA(const uint32_t* __restrict__ tot,
                        const float* __restrict__ s1, uint32_t* __restrict__ offs,
                        uint32_t* __restrict__ csc_src, float* __restrict__ csc_w){
    __shared__ uint32_t part[1024];
    int t = threadIdx.x;
    uint32_t local[8];
    uint32_t sum = 0;
    #pragma unroll
    for (int i = 0; i < 8; ++i){
        int idx = t*8 + i;
        uint32_t v = tot[idx] + (s1[idx] == 0.0f ? 1u : 0u);
        local[i] = v; sum += v;
    }
    part[t] = sum;
    __syncthreads();
    for (int off = 1; off < 1024; off <<= 1){
        uint32_t v = (t >= off) ? part[t - off] : 0u;
        __syncthreads();
        part[t] += v;
        __syncthreads();
    }
    uint32_t base = (t > 0) ? part[t-1] : 0u;
    #pragma unroll
    for (int i = 0; i < 8; ++i){
        int idx = t*8 + i;
        offs[idx] = base;
        uint32_t v = local[i];
        if (s1[idx] == 0.0f){            // zero-out-degree row -> self-loop at row end
            csc_src[base + v - 1] = (uint32_t)idx;
            csc_w[base + v - 1] = 1.0f;
        }
        base += v;
    }
    if (t == 1023) offs[NN] = base;
}

// scatter valid edges into CSC using LDS ranks (same blocking as k_hist2)
__global__ __launch_bounds__(512) void k_scatter(const int* __restrict__ ei,
                        const float* __restrict__ e_val, const float* __restrict__ s1,
                        const uint32_t* __restrict__ offs, const uint16_t* __restrict__ pre,
                        uint32_t* __restrict__ csc_src, float* __restrict__ csc_w){
    __shared__ uint32_t rnk[NN];
    int t = threadIdx.x, b = blockIdx.x;
    for (int i = t; i < NN; i += 512) rnk[i] = 0u;
    __syncthreads();
    int k0 = b * HB_EPB;
    for (int i = t; i < HB_EPB; i += 512){
        int k = k0 + i;
        float e = e_val[k];
        if (e >= 0.f){
            int src = ei[k], dst = ei[EE + k];
            uint32_t r = atomicAdd(&rnk[dst], 1u);
            uint32_t pos = offs[dst] + (uint32_t)pre[(size_t)dst*HB_NB + b] + r;
            csc_src[pos] = (uint32_t)src;
            csc_w[pos] = e / s1[src];
        }
    }
}

// one diffusion step: uout[i,:] = sum_{p in CSC row i} w[p]*uin[src[p],:] + Db[i,:] (+FW)
__global__ void k_spmv(const uint32_t* __restrict__ offs, const uint32_t* __restrict__ csrc,
                       const float* __restrict__ cw, const float* __restrict__ uin,
                       const float* __restrict__ Db, const float* __restrict__ FW,
                       float* __restrict__ uout){
    int row = blockIdx.x*4 + (threadIdx.x >> 6);
    int lane = threadIdx.x & 63;
    uint32_t s = offs[row], e = offs[row+1];
    float acc[CC];
    #pragma unroll
    for (int c = 0; c < CC; ++c) acc[c] = 0.f;
    for (uint32_t p = s + lane; p < e; p += 64){
        uint32_t src = csrc[p];
        float w = cw[p];
        const float2* u2 = (const float2*)(uin + (size_t)src*CC);
        #pragma unroll
        for (int q = 0; q < 5; ++q){
            float2 v = u2[q];
            acc[2*q]   += w * v.x;
            acc[2*q+1] += w * v.y;
        }
    }
    #pragma unroll
    for (int c = 0; c < CC; ++c){
        float r = acc[c];
        #pragma unroll
        for (int off = 32; off >= 1; off >>= 1) r += __shfl_xor(r, off);
        acc[c] = r;
    }
    if (lane == 0){
        const float* db = Db + row*CC;
        float* o = uout + row*CC;
        if (FW){
            const float* fw = FW + row*CC;
            #pragma unroll
            for (int c = 0; c < CC; ++c) o[c] = acc[c] + db[c] + fw[c];
        } else {
            #pragma unroll
            for (int c = 0; c < CC; ++c) o[c] = acc[c] + db[c];
        }
    }
}

extern "C" void kernel_launch(void* const* d_in, const int* in_sizes, int n_in,
                              void* d_out, int out_size, void* d_ws, size_t ws_size,
                              hipStream_t stream){
    const float* h    = (const float*)d_in[0];
    const float* W    = (const float*)d_in[1];
    const float* a    = (const float*)d_in[2];
    const float* W1   = (const float*)d_in[3];
    const float* feat = (const float*)d_in[4];
    const int* ei     = (const int*)d_in[5];
    const int* idx_tr = (const int*)d_in[6];
    const int* labels = (const int*)d_in[7];
    float* out = (float*)d_out;

    char* wsp = (char*)d_ws;
    auto alloc = [&](size_t bytes)->void*{
        void* p = (void*)wsp;
        wsp += (bytes + 255) & ~(size_t)255;
        return p;
    };
    uint32_t* htab   = (uint32_t*)alloc((size_t)HTAB_CAP*4);        // 2 MB
    float*    e_val  = (float*)   alloc((size_t)EE*4);              // 1 MB
    uint16_t* hp     = (uint16_t*)alloc((size_t)HB_NB*NN*2);        // 1 MB
    float*    s1p    = (float*)   alloc((size_t)HB_NB*NN*4);        // 2 MB
    uint16_t* pre    = (uint16_t*)alloc((size_t)NN*HB_NB*2);        // 1 MB
    uint32_t* tot    = (uint32_t*)alloc(NN*4);
    uint32_t* offs   = (uint32_t*)alloc((NN+1)*4);
    float*    s1     = (float*)   alloc(NN*4);
    uint32_t* csrc   = (uint32_t*)alloc((size_t)(EE+NN)*4);         // 1.05 MB
    float*    cw     = (float*)   alloc((size_t)(EE+NN)*4);         // 1.05 MB
    float*    v01    = (float*)   alloc(2*FF*4);
    float*    s_src  = (float*)   alloc(NN*4);
    float*    s_dst  = (float*)   alloc(NN*4);
    float*    FW     = (float*)   alloc((size_t)NN*CC*4);
    float*    cvec_unused = (float*)alloc(CC*4);
    float*    Db     = (float*)   alloc((size_t)NN*CC*4);
    float*    ua     = (float*)   alloc((size_t)NN*CC*4);
    float*    ub     = (float*)   alloc((size_t)NN*CC*4);
    (void)cvec_unused;

    hipMemsetAsync(htab, 0xFF, (size_t)HTAB_CAP*4, stream);

    k_v01    <<<1, FF, 0, stream>>>(W, a, v01);
    k_sdots  <<<NN/4, 256, 0, stream>>>(h, v01, s_src, s_dst);
    k_fw     <<<NN/4, 256, 0, stream>>>(feat, W1, FW);
    k_cvdb   <<<1, 1024, 0, stream>>>(idx_tr, labels, Db, ua);
    k_dedupG <<<EE/256, 256, 0, stream>>>(ei, s_src, s_dst, htab, e_val);
    k_hist2  <<<HB_NB, 512, 0, stream>>>(ei, e_val, hp, s1p);
    k_pre2   <<<NN/256, 256, 0, stream>>>(hp, s1p, pre, tot, s1);
    k_scanA  <<<1, 1024, 0, stream>>>(tot, s1, offs, csrc, cw);
    k_scatter<<<HB_NB, 512, 0, stream>>>(ei, e_val, s1, offs, pre, csrc, cw);

    float* cur = ua;
    float* nxt = ub;
    for (int t = 2; t <= 10; ++t){
        float* dst = (t == 10) ? out : nxt;
        const float* fwp = (t == 7) ? FW : nullptr;
        k_spmv<<<NN/4, 256, 0, stream>>>(offs, csrc, cw, cur, Db, fwp, dst);
        float* tmp = cur; cur = dst; nxt = tmp;
    }
}